// Round 9
// baseline (2321.253 us; speedup 1.0000x reference)
//
#include <hip/hip_runtime.h>

// 2-layer bidirectional LSTM, B=256 T=2048 D=64, H1=16/dir, H2=8/dir.
// R9 = R8 with the opaque-pin asm fixed (float4 can't be a tied asm operand
// on AMDGPU -> pin component-wise, 4 scalar "+v" ties per vector).
// Theory under test (from R7 post-mortem): VGPR_Count=56 proved weights were
// reloaded from global EVERY step — the in-loop asm "memory" clobbers
// (GST/WAITV) legally force the compiler to invalidate load-derived values,
// so it rematerializes w/u by re-loading, serializing global latency into
// each step. Fix:
//  - one-time weight loads -> asm("" : "+v"(x)) opaque fence per scalar:
//    the value becomes asm output, NOT a load; it cannot be rematerialized
//    from memory and must stay register-resident across the loop.
//  - GST has NO "memory" clobber (nothing in-kernel reads these stores) so
//    LDS x-reads can hoist/overlap; WAITV keeps clobber+sched_barrier (it
//    fences LDS ring-slot reuse).
//  - x staged through 4-slot LDS ring via global_load_lds DMA, 3 groups
//    ahead; hand-counted vmcnt identical to R7.
//  - serial path all-VALU: DPP row_ror butterfly + 3 shfl_xor gate exchange
//    (lane algebra unchanged since R4; absmax 9.8e-4).

constexpr int Bn = 256;
constexpr int Tn = 2048;

__device__ __forceinline__ float fast_rcp(float x) { return __builtin_amdgcn_rcpf(x); }
__device__ __forceinline__ float tanh_fast(float x) {
  return fmaf(2.0f, fast_rcp(1.0f + __expf(-2.0f * x)), -1.0f);
}

// DPP rotate-right by R within each 16-lane row: dst[l] = src[(l-R)&15].
template <int R>
__device__ __forceinline__ float rotr16(float v) {
  return __int_as_float(__builtin_amdgcn_mov_dpp(
      __float_as_int(v), 0x120 | R, 0xF, 0xF, true));
}

// Opaque register fence: value becomes asm output -> not rematerializable.
// float4 must be pinned component-wise (tied 128b operands unsupported).
#define OPQ4(v) asm("" : "+v"(v.x), "+v"(v.y), "+v"(v.z), "+v"(v.w));
#define OPQ1(v) asm("" : "+v"(v));

// Volatile store, NO memory clobber (see header comment).
#define GST(addr, val) \
  asm volatile("global_store_dword %0, %1, off" :: "v"(addr), "v"(val));

#define WAITV(N)                                              \
  do {                                                        \
    asm volatile("s_waitcnt vmcnt(" #N ")" ::: "memory");     \
    __builtin_amdgcn_sched_barrier(0);                        \
  } while (0)

// One DMA: 64 lanes x 16B = 1KB chunk. LDS dst = uniform base + lane*16.
#define DMA16(gsrc, ldst)                                         \
  __builtin_amdgcn_global_load_lds(                               \
      (const __attribute__((address_space(1))) float*)(gsrc),     \
      (__attribute__((address_space(3))) float*)(ldst), 16, 0, 0);

// 4 FMAs of LDS float4 xq_[I] * w##I into ACC.
#define FMAQ(ACC, I) { float4 v_ = xq_[I];                          \
    ACC = fmaf(v_.x, w##I.x, ACC); ACC = fmaf(v_.y, w##I.y, ACC);   \
    ACC = fmaf(v_.z, w##I.z, ACC); ACC = fmaf(v_.w, w##I.w, ACC); }

// ---------------- Layer 1: Din=64, H=16 ----------------
// grid = 2*B (blockIdx = b*2+dir), block = 64. lane = gate j; k=lane&15,
// grp=lane>>4 (0:i 1:f 2:g 3:o). Chunk = 4 rows x 64 floats = 1KB.
__global__ __launch_bounds__(64, 1) void l1_scan(
    const float* __restrict__ x,
    const float* __restrict__ wih_f, const float* __restrict__ whh_f,
    const float* __restrict__ bih_f, const float* __restrict__ bhh_f,
    const float* __restrict__ wih_b, const float* __restrict__ whh_b,
    const float* __restrict__ bih_b, const float* __restrict__ bhh_b,
    float* __restrict__ out1) {
  constexpr int NC = Tn / 4;          // 512 chunks
  const int lane = threadIdx.x;
  const int dir  = blockIdx.x & 1;
  const int b    = blockIdx.x >> 1;

  __shared__ float xr[4 * 256];       // 4-slot ring, 4KB

  const float* xb = x + (size_t)b * (Tn * 64);

  // Prologue: DMA first 3 chunks into their slots (slot = chunk & 3).
  {
    const int m0 = dir ? NC - 1 : 0;
    const int md = dir ? -1 : 1;
#pragma unroll
    for (int p = 0; p < 3; ++p) {
      const int mc = m0 + p * md;
      DMA16(xb + (size_t)mc * 256 + lane * 4, xr + (mc & 3) * 256)
    }
  }

  const float* wih = dir ? wih_b : wih_f;  // [64][64]
  const float* whh = dir ? whh_b : whh_f;  // [64][16]
  float bias = (dir ? bih_b : bih_f)[lane] + (dir ? bhh_b : bhh_f)[lane];

  const int k = lane & 15, grp = lane >> 4;
  const float gin  = (grp == 2) ? 2.0f : 1.0f;
  const float gout = (grp == 2) ? 2.0f : 1.0f;
  const float gsub = (grp == 2) ? -1.0f : 0.0f;

  // One-time weight loads -> opaque register pin.
  const float4* wr = reinterpret_cast<const float4*>(wih + lane * 64);
  float4 w0 = wr[0],  w1 = wr[1],  w2 = wr[2],  w3 = wr[3],
         w4 = wr[4],  w5 = wr[5],  w6 = wr[6],  w7 = wr[7],
         w8 = wr[8],  w9 = wr[9],  w10 = wr[10], w11 = wr[11],
         w12 = wr[12], w13 = wr[13], w14 = wr[14], w15 = wr[15];
  const float* whr = whh + lane * 16;
  float u0 = whr[k], u1 = whr[(k - 1) & 15], u2 = whr[(k - 2) & 15],
        u3 = whr[(k - 3) & 15], u4 = whr[(k - 4) & 15],
        u5 = whr[(k - 5) & 15], u6 = whr[(k - 6) & 15],
        u7 = whr[(k - 7) & 15], u8 = whr[(k - 8) & 15],
        u9 = whr[(k - 9) & 15], u10 = whr[(k - 10) & 15],
        u11 = whr[(k - 11) & 15], u12 = whr[(k - 12) & 15],
        u13 = whr[(k - 13) & 15], u14 = whr[(k - 14) & 15],
        u15 = whr[(k - 15) & 15];
  OPQ4(w0)  OPQ4(w1)  OPQ4(w2)  OPQ4(w3)  OPQ4(w4)  OPQ4(w5)
  OPQ4(w6)  OPQ4(w7)  OPQ4(w8)  OPQ4(w9)  OPQ4(w10) OPQ4(w11)
  OPQ4(w12) OPQ4(w13) OPQ4(w14) OPQ4(w15)
  OPQ1(u0)  OPQ1(u1)  OPQ1(u2)  OPQ1(u3)  OPQ1(u4)  OPQ1(u5)
  OPQ1(u6)  OPQ1(u7)  OPQ1(u8)  OPQ1(u9)  OPQ1(u10) OPQ1(u11)
  OPQ1(u12) OPQ1(u13) OPQ1(u14) OPQ1(u15)
  OPQ1(bias)

  const int ostep = dir ? -32 : 32;
  float* op = out1 + (size_t)b * (Tn * 32) + dir * 16 +
              (dir ? (size_t)(Tn - 1) * 32 : 0);

  float h = 0.0f, c = 0.0f;

#define STEP1(XROW) {                                                     \
    const float4* xq_ = reinterpret_cast<const float4*>(XROW);            \
    float a0 = bias, a1 = 0.f, a2 = 0.f, a3 = 0.f;                        \
    FMAQ(a0, 0)  FMAQ(a1, 1)  FMAQ(a2, 2)  FMAQ(a3, 3)                   \
    FMAQ(a0, 4)  FMAQ(a1, 5)  FMAQ(a2, 6)  FMAQ(a3, 7)                   \
    FMAQ(a0, 8)  FMAQ(a1, 9)  FMAQ(a2, 10) FMAQ(a3, 11)                  \
    FMAQ(a0, 12) FMAQ(a1, 13) FMAQ(a2, 14) FMAQ(a3, 15)                  \
    const float gx_ = (a0 + a1) + (a2 + a3);                              \
    float m0 = h * u0, m1 = 0.f, m2 = 0.f, m3 = 0.f;                      \
    m1 = fmaf(rotr16<1>(h),  u1,  m1);  m2 = fmaf(rotr16<2>(h),  u2,  m2); \
    m3 = fmaf(rotr16<3>(h),  u3,  m3);  m0 = fmaf(rotr16<4>(h),  u4,  m0); \
    m1 = fmaf(rotr16<5>(h),  u5,  m1);  m2 = fmaf(rotr16<6>(h),  u6,  m2); \
    m3 = fmaf(rotr16<7>(h),  u7,  m3);  m0 = fmaf(rotr16<8>(h),  u8,  m0); \
    m1 = fmaf(rotr16<9>(h),  u9,  m1);  m2 = fmaf(rotr16<10>(h), u10, m2); \
    m3 = fmaf(rotr16<11>(h), u11, m3);  m0 = fmaf(rotr16<12>(h), u12, m0); \
    m1 = fmaf(rotr16<13>(h), u13, m1);  m2 = fmaf(rotr16<14>(h), u14, m2); \
    m3 = fmaf(rotr16<15>(h), u15, m3);                                    \
    const float g_ = ((m0 + m1) + (m2 + m3)) + gx_;                       \
    const float sg_  = fast_rcp(1.0f + __expf(-gin * g_));                \
    const float val_ = fmaf(gout, sg_, gsub);                             \
    const float e1_ = __shfl_xor(val_, 16, 64);                           \
    const float e2_ = __shfl_xor(val_, 32, 64);                           \
    const float e3_ = __shfl_xor(val_, 48, 64);                           \
    const float iv_ = (grp == 0) ? val_ : (grp == 1) ? e1_ : (grp == 2) ? e2_ : e3_; \
    const float fv_ = (grp == 1) ? val_ : (grp == 0) ? e1_ : (grp == 3) ? e2_ : e3_; \
    const float gv_ = (grp == 2) ? val_ : (grp == 3) ? e1_ : (grp == 0) ? e2_ : e3_; \
    const float ov_ = (grp == 3) ? val_ : (grp == 2) ? e1_ : (grp == 1) ? e2_ : e3_; \
    c = fmaf(fv_, c, iv_ * gv_);                                          \
    h = ov_ * tanh_fast(c);                                               \
    if (lane < 16) { GST(op + lane, h) }                                  \
    op += ostep;                                                          \
  }

  // Group g consumes chunk mq (4 steps) and prefetches chunk mq±3.
#define GROUP1(NW, G) {                                                   \
    const int mq_ = dir ? (NC - 1 - (G)) : (G);                           \
    const float* sb_ = xr + (mq_ & 3) * 256;                              \
    WAITV(NW);                                                            \
    { const int mp_ = dir ? (mq_ - 3) : (mq_ + 3);                        \
      const int sl_ = mp_ & 3;                                            \
      const int mpc_ = mp_ < 0 ? 0 : (mp_ >= NC ? NC - 1 : mp_);          \
      DMA16(xb + (size_t)mpc_ * 256 + lane * 4, xr + sl_ * 256) }         \
    STEP1(sb_ + (dir ? 3 : 0) * 64)                                       \
    STEP1(sb_ + (dir ? 2 : 1) * 64)                                       \
    STEP1(sb_ + (dir ? 1 : 2) * 64)                                       \
    STEP1(sb_ + (dir ? 0 : 3) * 64)                                       \
  }

  GROUP1(2, 0)
  GROUP1(6, 1)
  GROUP1(10, 2)
#pragma unroll 1
  for (int g = 3; g < NC; ++g) {
    GROUP1(14, g)
  }
#undef GROUP1
#undef STEP1
}

// ---------------- Layer 2: Din=32, H=8 ----------------
// grid = 2*B, block = 64; lanes 32-63 replicate lanes 0-31 (j = lane&31).
// Chunk = 8 rows x 32 floats = 1KB.
__global__ __launch_bounds__(64, 1) void l2_scan(
    const float* __restrict__ in,   // out1 [B][T][32]
    const float* __restrict__ wih_f, const float* __restrict__ whh_f,
    const float* __restrict__ bih_f, const float* __restrict__ bhh_f,
    const float* __restrict__ wih_b, const float* __restrict__ whh_b,
    const float* __restrict__ bih_b, const float* __restrict__ bhh_b,
    float* __restrict__ out) {      // [B][T][16]
  constexpr int NC = Tn / 8;          // 256 chunks
  const int lane = threadIdx.x;
  const int j    = lane & 31;
  const int dir  = blockIdx.x & 1;
  const int b    = blockIdx.x >> 1;

  __shared__ float xr[4 * 256];       // 4-slot ring, 4KB

  const float* ib = in + (size_t)b * (Tn * 32);

  {
    const int m0 = dir ? NC - 1 : 0;
    const int md = dir ? -1 : 1;
#pragma unroll
    for (int p = 0; p < 3; ++p) {
      const int mc = m0 + p * md;
      DMA16(ib + (size_t)mc * 256 + lane * 4, xr + (mc & 3) * 256)
    }
  }

  const float* wih = dir ? wih_b : wih_f;  // [32][32]
  const float* whh = dir ? whh_b : whh_f;  // [32][8]
  float bias = (dir ? bih_b : bih_f)[j] + (dir ? bhh_b : bhh_f)[j];

  const int k = j & 7, grp = j >> 3;
  const float gin  = (grp == 2) ? 2.0f : 1.0f;
  const float gout = (grp == 2) ? 2.0f : 1.0f;
  const float gsub = (grp == 2) ? -1.0f : 0.0f;

  const float4* wr = reinterpret_cast<const float4*>(wih + j * 32);
  float4 w0 = wr[0], w1 = wr[1], w2 = wr[2], w3 = wr[3],
         w4 = wr[4], w5 = wr[5], w6 = wr[6], w7 = wr[7];
  const float* whr = whh + j * 8;
  float u0 = whr[k], u1 = whr[(k - 1) & 7], u2 = whr[(k - 2) & 7],
        u3 = whr[(k - 3) & 7], u4 = whr[(k - 4) & 7],
        u5 = whr[(k - 5) & 7], u6 = whr[(k - 6) & 7],
        u7 = whr[(k - 7) & 7];
  OPQ4(w0) OPQ4(w1) OPQ4(w2) OPQ4(w3) OPQ4(w4) OPQ4(w5) OPQ4(w6) OPQ4(w7)
  OPQ1(u0) OPQ1(u1) OPQ1(u2) OPQ1(u3) OPQ1(u4) OPQ1(u5) OPQ1(u6) OPQ1(u7)
  OPQ1(bias)

  const int ostep = dir ? -16 : 16;
  float* op = out + (size_t)b * (Tn * 16) + dir * 8 +
              (dir ? (size_t)(Tn - 1) * 16 : 0);

  float h = 0.0f, c = 0.0f;

#define STEP2(XROW) {                                                     \
    const float4* xq_ = reinterpret_cast<const float4*>(XROW);            \
    float a0 = bias, a1 = 0.f, a2 = 0.f, a3 = 0.f;                        \
    FMAQ(a0, 0) FMAQ(a1, 1) FMAQ(a2, 2) FMAQ(a3, 3)                      \
    FMAQ(a0, 4) FMAQ(a1, 5) FMAQ(a2, 6) FMAQ(a3, 7)                      \
    const float gx_ = (a0 + a1) + (a2 + a3);                              \
    float m0 = h * u0, m1 = 0.f, m2 = 0.f, m3 = 0.f;                      \
    m1 = fmaf(rotr16<1>(h), u1, m1);  m2 = fmaf(rotr16<2>(h), u2, m2);    \
    m3 = fmaf(rotr16<3>(h), u3, m3);  m0 = fmaf(rotr16<4>(h), u4, m0);    \
    m1 = fmaf(rotr16<5>(h), u5, m1);  m2 = fmaf(rotr16<6>(h), u6, m2);    \
    m3 = fmaf(rotr16<7>(h), u7, m3);                                      \
    const float g_ = ((m0 + m1) + (m2 + m3)) + gx_;                       \
    const float sg_  = fast_rcp(1.0f + __expf(-gin * g_));                \
    const float val_ = fmaf(gout, sg_, gsub);                             \
    const float e1_ = __shfl_xor(val_, 8, 64);                            \
    const float e2_ = __shfl_xor(val_, 16, 64);                           \
    const float e3_ = __shfl_xor(val_, 24, 64);                           \
    const float iv_ = (grp == 0) ? val_ : (grp == 1) ? e1_ : (grp == 2) ? e2_ : e3_; \
    const float fv_ = (grp == 1) ? val_ : (grp == 0) ? e1_ : (grp == 3) ? e2_ : e3_; \
    const float gv_ = (grp == 2) ? val_ : (grp == 3) ? e1_ : (grp == 0) ? e2_ : e3_; \
    const float ov_ = (grp == 3) ? val_ : (grp == 2) ? e1_ : (grp == 1) ? e2_ : e3_; \
    c = fmaf(fv_, c, iv_ * gv_);                                          \
    h = ov_ * tanh_fast(c);                                               \
    if (lane < 8) { GST(op + lane, h) }                                   \
    op += ostep;                                                          \
  }

#define GROUP2(NW, G) {                                                   \
    const int mq_ = dir ? (NC - 1 - (G)) : (G);                           \
    const float* sb_ = xr + (mq_ & 3) * 256;                              \
    WAITV(NW);                                                            \
    { const int mp_ = dir ? (mq_ - 3) : (mq_ + 3);                        \
      const int sl_ = mp_ & 3;                                            \
      const int mpc_ = mp_ < 0 ? 0 : (mp_ >= NC ? NC - 1 : mp_);          \
      DMA16(ib + (size_t)mpc_ * 256 + lane * 4, xr + sl_ * 256) }         \
    STEP2(sb_ + (dir ? 7 : 0) * 32)                                       \
    STEP2(sb_ + (dir ? 6 : 1) * 32)                                       \
    STEP2(sb_ + (dir ? 5 : 2) * 32)                                       \
    STEP2(sb_ + (dir ? 4 : 3) * 32)                                       \
    STEP2(sb_ + (dir ? 3 : 4) * 32)                                       \
    STEP2(sb_ + (dir ? 2 : 5) * 32)                                       \
    STEP2(sb_ + (dir ? 1 : 6) * 32)                                       \
    STEP2(sb_ + (dir ? 0 : 7) * 32)                                       \
  }

  GROUP2(2, 0)
  GROUP2(10, 1)
  GROUP2(18, 2)
#pragma unroll 1
  for (int g = 3; g < NC; ++g) {
    GROUP2(26, g)
  }
#undef GROUP2
#undef STEP2
}

extern "C" void kernel_launch(void* const* d_in, const int* in_sizes, int n_in,
                              void* d_out, int out_size, void* d_ws, size_t ws_size,
                              hipStream_t stream) {
  const float* x     = (const float*)d_in[0];
  const float* wih1f = (const float*)d_in[1];
  const float* whh1f = (const float*)d_in[2];
  const float* bih1f = (const float*)d_in[3];
  const float* bhh1f = (const float*)d_in[4];
  const float* wih2f = (const float*)d_in[9];
  const float* whh2f = (const float*)d_in[10];
  const float* bih2f = (const float*)d_in[11];
  const float* bhh2f = (const float*)d_in[12];
  const float* wih1b = (const float*)d_in[5];
  const float* whh1b = (const float*)d_in[6];
  const float* bih1b = (const float*)d_in[7];
  const float* bhh1b = (const float*)d_in[8];
  const float* wih2b = (const float*)d_in[13];
  const float* whh2b = (const float*)d_in[14];
  const float* bih2b = (const float*)d_in[15];
  const float* bhh2b = (const float*)d_in[16];

  float* out1 = (float*)d_ws;   // [B][T][32] fp32 = 67.1 MB
  float* outp = (float*)d_out;  // [B][T][16] fp32

  l1_scan<<<Bn * 2, 64, 0, stream>>>(x, wih1f, whh1f, bih1f, bhh1f,
                                     wih1b, whh1b, bih1b, bhh1b, out1);
  l2_scan<<<Bn * 2, 64, 0, stream>>>(out1, wih2f, whh2f, bih2f, bhh2f,
                                     wih2b, whh2b, bih2b, bhh2b, outp);
}

// Round 10
// 1443.208 us; speedup vs baseline: 1.6084x; 1.6084x over previous
//
#include <hip/hip_runtime.h>

// 2-layer bidirectional LSTM, B=256 T=2048 D=64, H1=16/dir, H2=8/dir.
// R10: gx-precompute architecture.
// R1-R9 lesson: the scan cannot hold ~80 per-lane weight floats — the RA
// budget pins VGPR_Count at ~56 and spills/reloads every step (R9: OPQ pin
// compiled, VGPR stayed 56, perf unchanged -> spill-restore, not remat).
// Fix: gx[bd][s][gate] = x.Wih^T + b_ih + b_hh precomputed by parallel GEMM
// kernels (no serial chain -> TLP hides everything), stored in SCAN order;
// the scan step becomes: 1 LDS read + 15-DPP butterfly (u: 16 regs) +
// activation + 3 shfl_xor + c/h update. ~35 live floats/lane -> no spills.
// Scan keeps R7's proven 4-slot LDS DMA ring + counted vmcnt skeleton
// (identical wait constants: per group still 1 DMA + 4/8 stores).
// ws layout: out1 (67MB) @0, gx1 (268MB) after; gx2 aliases gx1.
// Fallback (ws too small): R9 kernels verbatim (passed, 2321us).

constexpr int Bn = 256;
constexpr int Tn = 2048;

__device__ __forceinline__ float fast_rcp(float x) { return __builtin_amdgcn_rcpf(x); }
__device__ __forceinline__ float tanh_fast(float x) {
  return fmaf(2.0f, fast_rcp(1.0f + __expf(-2.0f * x)), -1.0f);
}

// DPP rotate-right by R within each 16-lane row: dst[l] = src[(l-R)&15].
template <int R>
__device__ __forceinline__ float rotr16(float v) {
  return __int_as_float(__builtin_amdgcn_mov_dpp(
      __float_as_int(v), 0x120 | R, 0xF, 0xF, true));
}

#define OPQ4(v) asm("" : "+v"(v.x), "+v"(v.y), "+v"(v.z), "+v"(v.w));
#define OPQ1(v) asm("" : "+v"(v));

#define GST(addr, val) \
  asm volatile("global_store_dword %0, %1, off" :: "v"(addr), "v"(val));

#define WAITV(N)                                              \
  do {                                                        \
    asm volatile("s_waitcnt vmcnt(" #N ")" ::: "memory");     \
    __builtin_amdgcn_sched_barrier(0);                        \
  } while (0)

#define DMA16(gsrc, ldst)                                         \
  __builtin_amdgcn_global_load_lds(                               \
      (const __attribute__((address_space(1))) float*)(gsrc),     \
      (__attribute__((address_space(3))) float*)(ldst), 16, 0, 0);

// uniform-x float4 * per-lane W quad
#define FMAU(ACC, I) { const float4 xv_ = x4[I];                    \
    ACC = fmaf(xv_.x, w##I.x, ACC); ACC = fmaf(xv_.y, w##I.y, ACC); \
    ACC = fmaf(xv_.z, w##I.z, ACC); ACC = fmaf(xv_.w, w##I.w, ACC); }

// LDS-x float4 * per-lane W quad (fallback kernels)
#define FMAQ(ACC, I) { float4 v_ = xq_[I];                          \
    ACC = fmaf(v_.x, w##I.x, ACC); ACC = fmaf(v_.y, w##I.y, ACC);   \
    ACC = fmaf(v_.z, w##I.z, ACC); ACC = fmaf(v_.w, w##I.w, ACC); }

// ==================== GEMM 1: gx1[bd][s][64] ====================
// grid = B*2*16 (bd major, 16 t-tiles); wave lane = gate (64/dir).
__global__ __launch_bounds__(64, 4) void gemm_gx1(
    const float* __restrict__ x,
    const float* __restrict__ wf, const float* __restrict__ bif,
    const float* __restrict__ bhf,
    const float* __restrict__ wb, const float* __restrict__ bib,
    const float* __restrict__ bhb,
    float* __restrict__ gx1) {
  constexpr int TILES = 16, TT = Tn / TILES;
  const int lane = threadIdx.x;
  const int bd   = blockIdx.x / TILES;
  const int tile = blockIdx.x % TILES;
  const int dir  = bd & 1, b = bd >> 1;

  const float* W = dir ? wb : wf;  // [64][64]
  float bias = (dir ? bib : bif)[lane] + (dir ? bhb : bhf)[lane];

  const float4* wr = reinterpret_cast<const float4*>(W + lane * 64);
  float4 w0 = wr[0],  w1 = wr[1],  w2 = wr[2],  w3 = wr[3],
         w4 = wr[4],  w5 = wr[5],  w6 = wr[6],  w7 = wr[7],
         w8 = wr[8],  w9 = wr[9],  w10 = wr[10], w11 = wr[11],
         w12 = wr[12], w13 = wr[13], w14 = wr[14], w15 = wr[15];
  OPQ4(w0)  OPQ4(w1)  OPQ4(w2)  OPQ4(w3)  OPQ4(w4)  OPQ4(w5)
  OPQ4(w6)  OPQ4(w7)  OPQ4(w8)  OPQ4(w9)  OPQ4(w10) OPQ4(w11)
  OPQ4(w12) OPQ4(w13) OPQ4(w14) OPQ4(w15) OPQ1(bias)

  float* gout = gx1 + (size_t)bd * Tn * 64;
  for (int tt = 0; tt < TT; ++tt) {
    const int t = tile * TT + tt;
    const float4* x4 =
        reinterpret_cast<const float4*>(x + ((size_t)b * Tn + t) * 64);
    float a0 = bias, a1 = 0.f, a2 = 0.f, a3 = 0.f;
    FMAU(a0, 0)  FMAU(a1, 1)  FMAU(a2, 2)  FMAU(a3, 3)
    FMAU(a0, 4)  FMAU(a1, 5)  FMAU(a2, 6)  FMAU(a3, 7)
    FMAU(a0, 8)  FMAU(a1, 9)  FMAU(a2, 10) FMAU(a3, 11)
    FMAU(a0, 12) FMAU(a1, 13) FMAU(a2, 14) FMAU(a3, 15)
    const float acc = (a0 + a1) + (a2 + a3);
    const int s = dir ? (Tn - 1 - t) : t;  // scan order
    gout[(size_t)s * 64 + lane] = acc;
  }
}

// ==================== GEMM 2: gx2[bd][s][32] ====================
// grid = B*16; lanes 0-31 = fwd gates, 32-63 = bwd gates (same t -> x uniform).
__global__ __launch_bounds__(64, 4) void gemm_gx2(
    const float* __restrict__ in,   // out1 [B][T][32]
    const float* __restrict__ wf, const float* __restrict__ bif,
    const float* __restrict__ bhf,
    const float* __restrict__ wb, const float* __restrict__ bib,
    const float* __restrict__ bhb,
    float* __restrict__ gx2) {
  constexpr int TILES = 16, TT = Tn / TILES;
  const int lane = threadIdx.x;
  const int g = lane & 31, half = lane >> 5;
  const int b = blockIdx.x / TILES, tile = blockIdx.x % TILES;

  const float* W = half ? wb : wf;  // [32][32]
  float bias = (half ? bib : bif)[g] + (half ? bhb : bhf)[g];

  const float4* wr = reinterpret_cast<const float4*>(W + g * 32);
  float4 w0 = wr[0], w1 = wr[1], w2 = wr[2], w3 = wr[3],
         w4 = wr[4], w5 = wr[5], w6 = wr[6], w7 = wr[7];
  OPQ4(w0) OPQ4(w1) OPQ4(w2) OPQ4(w3) OPQ4(w4) OPQ4(w5) OPQ4(w6) OPQ4(w7)
  OPQ1(bias)

  for (int tt = 0; tt < TT; ++tt) {
    const int t = tile * TT + tt;
    const float4* x4 =
        reinterpret_cast<const float4*>(in + ((size_t)b * Tn + t) * 32);
    float a0 = bias, a1 = 0.f, a2 = 0.f, a3 = 0.f;
    FMAU(a0, 0) FMAU(a1, 1) FMAU(a2, 2) FMAU(a3, 3)
    FMAU(a0, 4) FMAU(a1, 5) FMAU(a2, 6) FMAU(a3, 7)
    const float acc = (a0 + a1) + (a2 + a3);
    const int s = half ? (Tn - 1 - t) : t;
    gx2[((size_t)(b * 2 + half) * Tn + s) * 32 + g] = acc;
  }
}

// ==================== Scan 1 (gx-fed): H=16 ====================
// grid = 2*B (blockIdx = bd), block = 64. Chunk = 4 s-rows x 64 = 1KB.
__global__ __launch_bounds__(64, 1) void l1_scan_gx(
    const float* __restrict__ gx1,
    const float* __restrict__ whh_f, const float* __restrict__ whh_b,
    float* __restrict__ out1) {
  constexpr int NC = Tn / 4;
  const int lane = threadIdx.x;
  const int dir  = blockIdx.x & 1;
  const int b    = blockIdx.x >> 1;

  __shared__ float xr[4 * 256];
  const float* gxb = gx1 + (size_t)blockIdx.x * Tn * 64;

#pragma unroll
  for (int p = 0; p < 3; ++p)
    DMA16(gxb + (size_t)p * 256 + lane * 4, xr + p * 256)

  const float* whh = dir ? whh_b : whh_f;  // [64][16]
  const int k = lane & 15, grp = lane >> 4;
  const float* whr = whh + lane * 16;
  float u0 = whr[k], u1 = whr[(k - 1) & 15], u2 = whr[(k - 2) & 15],
        u3 = whr[(k - 3) & 15], u4 = whr[(k - 4) & 15],
        u5 = whr[(k - 5) & 15], u6 = whr[(k - 6) & 15],
        u7 = whr[(k - 7) & 15], u8 = whr[(k - 8) & 15],
        u9 = whr[(k - 9) & 15], u10 = whr[(k - 10) & 15],
        u11 = whr[(k - 11) & 15], u12 = whr[(k - 12) & 15],
        u13 = whr[(k - 13) & 15], u14 = whr[(k - 14) & 15],
        u15 = whr[(k - 15) & 15];
  OPQ1(u0)  OPQ1(u1)  OPQ1(u2)  OPQ1(u3)  OPQ1(u4)  OPQ1(u5)
  OPQ1(u6)  OPQ1(u7)  OPQ1(u8)  OPQ1(u9)  OPQ1(u10) OPQ1(u11)
  OPQ1(u12) OPQ1(u13) OPQ1(u14) OPQ1(u15)

  const float gin  = (grp == 2) ? 2.0f : 1.0f;
  const float gout = (grp == 2) ? 2.0f : 1.0f;
  const float gsub = (grp == 2) ? -1.0f : 0.0f;

  const int ostep = dir ? -32 : 32;
  float* op = out1 + (size_t)b * Tn * 32 + dir * 16 +
              (dir ? (size_t)(Tn - 1) * 32 : 0);

  float h = 0.0f, c = 0.0f;

#define STEP1(GX) {                                                       \
    float m0 = fmaf(h, u0, (GX)), m1 = 0.f, m2 = 0.f, m3 = 0.f;           \
    m1 = fmaf(rotr16<1>(h),  u1,  m1);  m2 = fmaf(rotr16<2>(h),  u2,  m2); \
    m3 = fmaf(rotr16<3>(h),  u3,  m3);  m0 = fmaf(rotr16<4>(h),  u4,  m0); \
    m1 = fmaf(rotr16<5>(h),  u5,  m1);  m2 = fmaf(rotr16<6>(h),  u6,  m2); \
    m3 = fmaf(rotr16<7>(h),  u7,  m3);  m0 = fmaf(rotr16<8>(h),  u8,  m0); \
    m1 = fmaf(rotr16<9>(h),  u9,  m1);  m2 = fmaf(rotr16<10>(h), u10, m2); \
    m3 = fmaf(rotr16<11>(h), u11, m3);  m0 = fmaf(rotr16<12>(h), u12, m0); \
    m1 = fmaf(rotr16<13>(h), u13, m1);  m2 = fmaf(rotr16<14>(h), u14, m2); \
    m3 = fmaf(rotr16<15>(h), u15, m3);                                    \
    const float g_ = (m0 + m1) + (m2 + m3);                               \
    const float sg_  = fast_rcp(1.0f + __expf(-gin * g_));                \
    const float val_ = fmaf(gout, sg_, gsub);                             \
    const float e1_ = __shfl_xor(val_, 16, 64);                           \
    const float e2_ = __shfl_xor(val_, 32, 64);                           \
    const float e3_ = __shfl_xor(val_, 48, 64);                           \
    const float iv_ = (grp == 0) ? val_ : (grp == 1) ? e1_ : (grp == 2) ? e2_ : e3_; \
    const float fv_ = (grp == 1) ? val_ : (grp == 0) ? e1_ : (grp == 3) ? e2_ : e3_; \
    const float gv_ = (grp == 2) ? val_ : (grp == 3) ? e1_ : (grp == 0) ? e2_ : e3_; \
    const float ov_ = (grp == 3) ? val_ : (grp == 2) ? e1_ : (grp == 1) ? e2_ : e3_; \
    c = fmaf(fv_, c, iv_ * gv_);                                          \
    h = ov_ * tanh_fast(c);                                               \
    if (lane < 16) { GST(op + lane, h) }                                  \
    op += ostep;                                                          \
  }

  // Per group: 1 DMA + 4 stores -> same wait constants as R7.
#define GROUP1(NW, G) {                                                   \
    WAITV(NW);                                                            \
    const float* sb_ = xr + ((G) & 3) * 256;                              \
    const float q0_ = sb_[lane];                                          \
    const float q1_ = sb_[64 + lane];                                     \
    const float q2_ = sb_[128 + lane];                                    \
    const float q3_ = sb_[192 + lane];                                    \
    { const int mp_ = (G) + 3;                                            \
      const int mpc_ = (mp_ < NC) ? mp_ : NC - 1;                         \
      DMA16(gxb + (size_t)mpc_ * 256 + lane * 4, xr + (mp_ & 3) * 256) }  \
    STEP1(q0_) STEP1(q1_) STEP1(q2_) STEP1(q3_)                           \
  }

  GROUP1(2, 0)
  GROUP1(6, 1)
  GROUP1(10, 2)
#pragma unroll 1
  for (int g = 3; g < NC; ++g) {
    GROUP1(14, g)
  }
#undef GROUP1
#undef STEP1
}

// ==================== Scan 2 (gx-fed): H=8 ====================
// grid = 2*B, block = 64; lanes 32-63 replicate (j = lane&31).
// Chunk = 8 s-rows x 32 = 1KB.
__global__ __launch_bounds__(64, 1) void l2_scan_gx(
    const float* __restrict__ gx2,
    const float* __restrict__ whh_f, const float* __restrict__ whh_b,
    float* __restrict__ out) {
  constexpr int NC = Tn / 8;
  const int lane = threadIdx.x;
  const int j    = lane & 31;
  const int dir  = blockIdx.x & 1;
  const int b    = blockIdx.x >> 1;

  __shared__ float xr[4 * 256];
  const float* gxb = gx2 + (size_t)blockIdx.x * Tn * 32;

#pragma unroll
  for (int p = 0; p < 3; ++p)
    DMA16(gxb + (size_t)p * 256 + lane * 4, xr + p * 256)

  const float* whh = dir ? whh_b : whh_f;  // [32][8]
  const int k = j & 7, grp = j >> 3;
  const float* whr = whh + j * 8;
  float u0 = whr[k], u1 = whr[(k - 1) & 7], u2 = whr[(k - 2) & 7],
        u3 = whr[(k - 3) & 7], u4 = whr[(k - 4) & 7],
        u5 = whr[(k - 5) & 7], u6 = whr[(k - 6) & 7],
        u7 = whr[(k - 7) & 7];
  OPQ1(u0) OPQ1(u1) OPQ1(u2) OPQ1(u3) OPQ1(u4) OPQ1(u5) OPQ1(u6) OPQ1(u7)

  const float gin  = (grp == 2) ? 2.0f : 1.0f;
  const float gout = (grp == 2) ? 2.0f : 1.0f;
  const float gsub = (grp == 2) ? -1.0f : 0.0f;

  const int ostep = dir ? -16 : 16;
  float* op = out + (size_t)b * Tn * 16 + dir * 8 +
              (dir ? (size_t)(Tn - 1) * 16 : 0);

  float h = 0.0f, c = 0.0f;

#define STEP2(GX) {                                                       \
    float m0 = fmaf(h, u0, (GX)), m1 = 0.f, m2 = 0.f, m3 = 0.f;           \
    m1 = fmaf(rotr16<1>(h), u1, m1);  m2 = fmaf(rotr16<2>(h), u2, m2);    \
    m3 = fmaf(rotr16<3>(h), u3, m3);  m0 = fmaf(rotr16<4>(h), u4, m0);    \
    m1 = fmaf(rotr16<5>(h), u5, m1);  m2 = fmaf(rotr16<6>(h), u6, m2);    \
    m3 = fmaf(rotr16<7>(h), u7, m3);                                      \
    const float g_ = (m0 + m1) + (m2 + m3);                               \
    const float sg_  = fast_rcp(1.0f + __expf(-gin * g_));                \
    const float val_ = fmaf(gout, sg_, gsub);                             \
    const float e1_ = __shfl_xor(val_, 8, 64);                            \
    const float e2_ = __shfl_xor(val_, 16, 64);                           \
    const float e3_ = __shfl_xor(val_, 24, 64);                           \
    const float iv_ = (grp == 0) ? val_ : (grp == 1) ? e1_ : (grp == 2) ? e2_ : e3_; \
    const float fv_ = (grp == 1) ? val_ : (grp == 0) ? e1_ : (grp == 3) ? e2_ : e3_; \
    const float gv_ = (grp == 2) ? val_ : (grp == 3) ? e1_ : (grp == 0) ? e2_ : e3_; \
    const float ov_ = (grp == 3) ? val_ : (grp == 2) ? e1_ : (grp == 1) ? e2_ : e3_; \
    c = fmaf(fv_, c, iv_ * gv_);                                          \
    h = ov_ * tanh_fast(c);                                               \
    if (lane < 8) { GST(op + lane, h) }                                   \
    op += ostep;                                                          \
  }

#define GROUP2(NW, G) {                                                   \
    WAITV(NW);                                                            \
    const float* sb_ = xr + ((G) & 3) * 256;                              \
    const float q0_ = sb_[j];            const float q1_ = sb_[32 + j];   \
    const float q2_ = sb_[64 + j];       const float q3_ = sb_[96 + j];   \
    const float q4_ = sb_[128 + j];      const float q5_ = sb_[160 + j];  \
    const float q6_ = sb_[192 + j];      const float q7_ = sb_[224 + j];  \
    { const int mp_ = (G) + 3;                                            \
      const int mpc_ = (mp_ < NC) ? mp_ : NC - 1;                         \
      DMA16(gxb + (size_t)mpc_ * 256 + lane * 4, xr + (mp_ & 3) * 256) }  \
    STEP2(q0_) STEP2(q1_) STEP2(q2_) STEP2(q3_)                           \
    STEP2(q4_) STEP2(q5_) STEP2(q6_) STEP2(q7_)                           \
  }

  GROUP2(2, 0)
  GROUP2(10, 1)
  GROUP2(18, 2)
#pragma unroll 1
  for (int g = 3; g < NC; ++g) {
    GROUP2(26, g)
  }
#undef GROUP2
#undef STEP2
}

// ==================== Fallback (R9, proven): weights in scan ====================
__global__ __launch_bounds__(64, 1) void l1_scan_fb(
    const float* __restrict__ x,
    const float* __restrict__ wih_f, const float* __restrict__ whh_f,
    const float* __restrict__ bih_f, const float* __restrict__ bhh_f,
    const float* __restrict__ wih_b, const float* __restrict__ whh_b,
    const float* __restrict__ bih_b, const float* __restrict__ bhh_b,
    float* __restrict__ out1) {
  constexpr int NC = Tn / 4;
  const int lane = threadIdx.x;
  const int dir  = blockIdx.x & 1;
  const int b    = blockIdx.x >> 1;
  __shared__ float xr[4 * 256];
  const float* xb = x + (size_t)b * (Tn * 64);
  {
    const int m0 = dir ? NC - 1 : 0;
    const int md = dir ? -1 : 1;
#pragma unroll
    for (int p = 0; p < 3; ++p) {
      const int mc = m0 + p * md;
      DMA16(xb + (size_t)mc * 256 + lane * 4, xr + (mc & 3) * 256)
    }
  }
  const float* wih = dir ? wih_b : wih_f;
  const float* whh = dir ? whh_b : whh_f;
  float bias = (dir ? bih_b : bih_f)[lane] + (dir ? bhh_b : bhh_f)[lane];
  const int k = lane & 15, grp = lane >> 4;
  const float gin  = (grp == 2) ? 2.0f : 1.0f;
  const float gout = (grp == 2) ? 2.0f : 1.0f;
  const float gsub = (grp == 2) ? -1.0f : 0.0f;
  const float4* wr = reinterpret_cast<const float4*>(wih + lane * 64);
  float4 w0 = wr[0],  w1 = wr[1],  w2 = wr[2],  w3 = wr[3],
         w4 = wr[4],  w5 = wr[5],  w6 = wr[6],  w7 = wr[7],
         w8 = wr[8],  w9 = wr[9],  w10 = wr[10], w11 = wr[11],
         w12 = wr[12], w13 = wr[13], w14 = wr[14], w15 = wr[15];
  const float* whr = whh + lane * 16;
  float u0 = whr[k], u1 = whr[(k - 1) & 15], u2 = whr[(k - 2) & 15],
        u3 = whr[(k - 3) & 15], u4 = whr[(k - 4) & 15],
        u5 = whr[(k - 5) & 15], u6 = whr[(k - 6) & 15],
        u7 = whr[(k - 7) & 15], u8 = whr[(k - 8) & 15],
        u9 = whr[(k - 9) & 15], u10 = whr[(k - 10) & 15],
        u11 = whr[(k - 11) & 15], u12 = whr[(k - 12) & 15],
        u13 = whr[(k - 13) & 15], u14 = whr[(k - 14) & 15],
        u15 = whr[(k - 15) & 15];
  const int ostep = dir ? -32 : 32;
  float* op = out1 + (size_t)b * (Tn * 32) + dir * 16 +
              (dir ? (size_t)(Tn - 1) * 32 : 0);
  float h = 0.0f, c = 0.0f;
#define STEP1F(XROW) {                                                    \
    const float4* xq_ = reinterpret_cast<const float4*>(XROW);            \
    float a0 = bias, a1 = 0.f, a2 = 0.f, a3 = 0.f;                        \
    FMAQ(a0, 0)  FMAQ(a1, 1)  FMAQ(a2, 2)  FMAQ(a3, 3)                   \
    FMAQ(a0, 4)  FMAQ(a1, 5)  FMAQ(a2, 6)  FMAQ(a3, 7)                   \
    FMAQ(a0, 8)  FMAQ(a1, 9)  FMAQ(a2, 10) FMAQ(a3, 11)                  \
    FMAQ(a0, 12) FMAQ(a1, 13) FMAQ(a2, 14) FMAQ(a3, 15)                  \
    const float gx_ = (a0 + a1) + (a2 + a3);                              \
    float m0 = h * u0, m1 = 0.f, m2 = 0.f, m3 = 0.f;                      \
    m1 = fmaf(rotr16<1>(h),  u1,  m1);  m2 = fmaf(rotr16<2>(h),  u2,  m2); \
    m3 = fmaf(rotr16<3>(h),  u3,  m3);  m0 = fmaf(rotr16<4>(h),  u4,  m0); \
    m1 = fmaf(rotr16<5>(h),  u5,  m1);  m2 = fmaf(rotr16<6>(h),  u6,  m2); \
    m3 = fmaf(rotr16<7>(h),  u7,  m3);  m0 = fmaf(rotr16<8>(h),  u8,  m0); \
    m1 = fmaf(rotr16<9>(h),  u9,  m1);  m2 = fmaf(rotr16<10>(h), u10, m2); \
    m3 = fmaf(rotr16<11>(h), u11, m3);  m0 = fmaf(rotr16<12>(h), u12, m0); \
    m1 = fmaf(rotr16<13>(h), u13, m1);  m2 = fmaf(rotr16<14>(h), u14, m2); \
    m3 = fmaf(rotr16<15>(h), u15, m3);                                    \
    const float g_ = ((m0 + m1) + (m2 + m3)) + gx_;                       \
    const float sg_  = fast_rcp(1.0f + __expf(-gin * g_));                \
    const float val_ = fmaf(gout, sg_, gsub);                             \
    const float e1_ = __shfl_xor(val_, 16, 64);                           \
    const float e2_ = __shfl_xor(val_, 32, 64);                           \
    const float e3_ = __shfl_xor(val_, 48, 64);                           \
    const float iv_ = (grp == 0) ? val_ : (grp == 1) ? e1_ : (grp == 2) ? e2_ : e3_; \
    const float fv_ = (grp == 1) ? val_ : (grp == 0) ? e1_ : (grp == 3) ? e2_ : e3_; \
    const float gv_ = (grp == 2) ? val_ : (grp == 3) ? e1_ : (grp == 0) ? e2_ : e3_; \
    const float ov_ = (grp == 3) ? val_ : (grp == 2) ? e1_ : (grp == 1) ? e2_ : e3_; \
    c = fmaf(fv_, c, iv_ * gv_);                                          \
    h = ov_ * tanh_fast(c);                                               \
    if (lane < 16) { GST(op + lane, h) }                                  \
    op += ostep;                                                          \
  }
#define GROUP1F(NW, G) {                                                  \
    const int mq_ = dir ? (NC - 1 - (G)) : (G);                           \
    const float* sb_ = xr + (mq_ & 3) * 256;                              \
    WAITV(NW);                                                            \
    { const int mp_ = dir ? (mq_ - 3) : (mq_ + 3);                        \
      const int sl_ = mp_ & 3;                                            \
      const int mpc_ = mp_ < 0 ? 0 : (mp_ >= NC ? NC - 1 : mp_);          \
      DMA16(xb + (size_t)mpc_ * 256 + lane * 4, xr + sl_ * 256) }         \
    STEP1F(sb_ + (dir ? 3 : 0) * 64)                                      \
    STEP1F(sb_ + (dir ? 2 : 1) * 64)                                      \
    STEP1F(sb_ + (dir ? 1 : 2) * 64)                                      \
    STEP1F(sb_ + (dir ? 0 : 3) * 64)                                      \
  }
  GROUP1F(2, 0)
  GROUP1F(6, 1)
  GROUP1F(10, 2)
#pragma unroll 1
  for (int g = 3; g < NC; ++g) {
    GROUP1F(14, g)
  }
#undef GROUP1F
#undef STEP1F
}

__global__ __launch_bounds__(64, 1) void l2_scan_fb(
    const float* __restrict__ in,
    const float* __restrict__ wih_f, const float* __restrict__ whh_f,
    const float* __restrict__ bih_f, const float* __restrict__ bhh_f,
    const float* __restrict__ wih_b, const float* __restrict__ whh_b,
    const float* __restrict__ bih_b, const float* __restrict__ bhh_b,
    float* __restrict__ out) {
  constexpr int NC = Tn / 8;
  const int lane = threadIdx.x;
  const int j    = lane & 31;
  const int dir  = blockIdx.x & 1;
  const int b    = blockIdx.x >> 1;
  __shared__ float xr[4 * 256];
  const float* ib = in + (size_t)b * (Tn * 32);
  {
    const int m0 = dir ? NC - 1 : 0;
    const int md = dir ? -1 : 1;
#pragma unroll
    for (int p = 0; p < 3; ++p) {
      const int mc = m0 + p * md;
      DMA16(ib + (size_t)mc * 256 + lane * 4, xr + (mc & 3) * 256)
    }
  }
  const float* wih = dir ? wih_b : wih_f;
  const float* whh = dir ? whh_b : whh_f;
  float bias = (dir ? bih_b : bih_f)[j] + (dir ? bhh_b : bhh_f)[j];
  const int k = j & 7, grp = j >> 3;
  const float gin  = (grp == 2) ? 2.0f : 1.0f;
  const float gout = (grp == 2) ? 2.0f : 1.0f;
  const float gsub = (grp == 2) ? -1.0f : 0.0f;
  const float4* wr = reinterpret_cast<const float4*>(wih + j * 32);
  float4 w0 = wr[0], w1 = wr[1], w2 = wr[2], w3 = wr[3],
         w4 = wr[4], w5 = wr[5], w6 = wr[6], w7 = wr[7];
  const float* whr = whh + j * 8;
  float u0 = whr[k], u1 = whr[(k - 1) & 7], u2 = whr[(k - 2) & 7],
        u3 = whr[(k - 3) & 7], u4 = whr[(k - 4) & 7],
        u5 = whr[(k - 5) & 7], u6 = whr[(k - 6) & 7],
        u7 = whr[(k - 7) & 7];
  const int ostep = dir ? -16 : 16;
  float* op = out + (size_t)b * (Tn * 16) + dir * 8 +
              (dir ? (size_t)(Tn - 1) * 16 : 0);
  float h = 0.0f, c = 0.0f;
#define STEP2F(XROW) {                                                    \
    const float4* xq_ = reinterpret_cast<const float4*>(XROW);            \
    float a0 = bias, a1 = 0.f, a2 = 0.f, a3 = 0.f;                        \
    FMAQ(a0, 0) FMAQ(a1, 1) FMAQ(a2, 2) FMAQ(a3, 3)                      \
    FMAQ(a0, 4) FMAQ(a1, 5) FMAQ(a2, 6) FMAQ(a3, 7)                      \
    const float gx_ = (a0 + a1) + (a2 + a3);                              \
    float m0 = h * u0, m1 = 0.f, m2 = 0.f, m3 = 0.f;                      \
    m1 = fmaf(rotr16<1>(h), u1, m1);  m2 = fmaf(rotr16<2>(h), u2, m2);    \
    m3 = fmaf(rotr16<3>(h), u3, m3);  m0 = fmaf(rotr16<4>(h), u4, m0);    \
    m1 = fmaf(rotr16<5>(h), u5, m1);  m2 = fmaf(rotr16<6>(h), u6, m2);    \
    m3 = fmaf(rotr16<7>(h), u7, m3);                                      \
    const float g_ = ((m0 + m1) + (m2 + m3)) + gx_;                       \
    const float sg_  = fast_rcp(1.0f + __expf(-gin * g_));                \
    const float val_ = fmaf(gout, sg_, gsub);                             \
    const float e1_ = __shfl_xor(val_, 8, 64);                            \
    const float e2_ = __shfl_xor(val_, 16, 64);                           \
    const float e3_ = __shfl_xor(val_, 24, 64);                           \
    const float iv_ = (grp == 0) ? val_ : (grp == 1) ? e1_ : (grp == 2) ? e2_ : e3_; \
    const float fv_ = (grp == 1) ? val_ : (grp == 0) ? e1_ : (grp == 3) ? e2_ : e3_; \
    const float gv_ = (grp == 2) ? val_ : (grp == 3) ? e1_ : (grp == 0) ? e2_ : e3_; \
    const float ov_ = (grp == 3) ? val_ : (grp == 2) ? e1_ : (grp == 1) ? e2_ : e3_; \
    c = fmaf(fv_, c, iv_ * gv_);                                          \
    h = ov_ * tanh_fast(c);                                               \
    if (lane < 8) { GST(op + lane, h) }                                   \
    op += ostep;                                                          \
  }
#define GROUP2F(NW, G) {                                                  \
    const int mq_ = dir ? (NC - 1 - (G)) : (G);                           \
    const float* sb_ = xr + (mq_ & 3) * 256;                              \
    WAITV(NW);                                                            \
    { const int mp_ = dir ? (mq_ - 3) : (mq_ + 3);                        \
      const int sl_ = mp_ & 3;                                            \
      const int mpc_ = mp_ < 0 ? 0 : (mp_ >= NC ? NC - 1 : mp_);          \
      DMA16(ib + (size_t)mpc_ * 256 + lane * 4, xr + sl_ * 256) }         \
    STEP2F(sb_ + (dir ? 7 : 0) * 32)                                      \
    STEP2F(sb_ + (dir ? 6 : 1) * 32)                                      \
    STEP2F(sb_ + (dir ? 5 : 2) * 32)                                      \
    STEP2F(sb_ + (dir ? 4 : 3) * 32)                                      \
    STEP2F(sb_ + (dir ? 3 : 4) * 32)                                      \
    STEP2F(sb_ + (dir ? 2 : 5) * 32)                                      \
    STEP2F(sb_ + (dir ? 1 : 6) * 32)                                      \
    STEP2F(sb_ + (dir ? 0 : 7) * 32)                                      \
  }
  GROUP2F(2, 0)
  GROUP2F(10, 1)
  GROUP2F(18, 2)
#pragma unroll 1
  for (int g = 3; g < NC; ++g) {
    GROUP2F(26, g)
  }
#undef GROUP2F
#undef STEP2F
}

extern "C" void kernel_launch(void* const* d_in, const int* in_sizes, int n_in,
                              void* d_out, int out_size, void* d_ws, size_t ws_size,
                              hipStream_t stream) {
  const float* x     = (const float*)d_in[0];
  const float* wih1f = (const float*)d_in[1];
  const float* whh1f = (const float*)d_in[2];
  const float* bih1f = (const float*)d_in[3];
  const float* bhh1f = (const float*)d_in[4];
  const float* wih1b = (const float*)d_in[5];
  const float* whh1b = (const float*)d_in[6];
  const float* bih1b = (const float*)d_in[7];
  const float* bhh1b = (const float*)d_in[8];
  const float* wih2f = (const float*)d_in[9];
  const float* whh2f = (const float*)d_in[10];
  const float* bih2f = (const float*)d_in[11];
  const float* bhh2f = (const float*)d_in[12];
  const float* wih2b = (const float*)d_in[13];
  const float* whh2b = (const float*)d_in[14];
  const float* bih2b = (const float*)d_in[15];
  const float* bhh2b = (const float*)d_in[16];

  float* out1 = (float*)d_ws;                       // [B][T][32] = 67.1 MB
  float* outp = (float*)d_out;                      // [B][T][16]

  const size_t out1F = (size_t)Bn * Tn * 32;        // floats
  const size_t gx1F  = (size_t)Bn * 2 * Tn * 64;    // floats (268.4 MB)
  const size_t needB = (out1F + gx1F) * sizeof(float);

  if (ws_size >= needB) {
    float* gx1 = (float*)d_ws + out1F;              // [2B][T][64]
    float* gx2 = gx1;                               // aliases gx1 (dead after scan1)
    gemm_gx1<<<Bn * 2 * 16, 64, 0, stream>>>(
        x, wih1f, bih1f, bhh1f, wih1b, bih1b, bhh1b, gx1);
    l1_scan_gx<<<Bn * 2, 64, 0, stream>>>(gx1, whh1f, whh1b, out1);
    gemm_gx2<<<Bn * 16, 64, 0, stream>>>(
        out1, wih2f, bih2f, bhh2f, wih2b, bih2b, bhh2b, gx2);
    l2_scan_gx<<<Bn * 2, 64, 0, stream>>>(gx2, whh2f, whh2b, outp);
  } else {
    l1_scan_fb<<<Bn * 2, 64, 0, stream>>>(x, wih1f, whh1f, bih1f, bhh1f,
                                          wih1b, whh1b, bih1b, bhh1b, out1);
    l2_scan_fb<<<Bn * 2, 64, 0, stream>>>(out1, wih2f, whh2f, bih2f, bhh2f,
                                          wih2b, whh2b, bih2b, bhh2b, outp);
  }
}